// Round 17
// baseline (54.099 us; speedup 1.0000x reference)
//
#include <hip/hip_runtime.h>
#include <math.h>

// Problem constants
#define B_ 16
#define NL_ 12
#define L1_ 197
#define D_ 768
#define E_ 4
#define K_ 3
#define C_ 21
#define IMG_ 224
#define LP_ 196
#define NJ_ 84      // real output cols (E*C)
#define MT_ 52      // m-rows per gemm block (52,52,52,40)
#define KSTEPS 24   // 768 / 32

typedef __attribute__((ext_vector_type(8))) short short8;
typedef __attribute__((ext_vector_type(4))) float f32x4;
typedef unsigned short ushort_t;

__device__ __forceinline__ ushort_t bf16rne(float x) {
    unsigned u = __float_as_uint(x);
    unsigned r = (u + 0x7FFFu + ((u >> 16) & 1u)) >> 16;
    return (ushort_t)r;
}

// direct global -> LDS, 16 bytes per lane (dest = uniform base + lane*16)
__device__ __forceinline__ void glds16(const void* g, void* l) {
    __builtin_amdgcn_global_load_lds(
        (const __attribute__((address_space(1))) unsigned int*)g,
        (__attribute__((address_space(3))) unsigned int*)l, 16, 0, 0);
}

// per-(b,e) gating: softmax over 12 layers -> top3 (ties: lowest idx) -> softmax
__device__ __forceinline__ void select_be(const float* __restrict__ gs, int b, int e,
                                          int idx[3], float w[3]) {
    float p[NL_]; float mx = -1e30f;
    #pragma unroll
    for (int nl = 0; nl < NL_; ++nl) { float v = gs[(b * NL_ + nl) * E_ + e]; p[nl] = v; mx = fmaxf(mx, v); }
    float ss = 0.f;
    #pragma unroll
    for (int nl = 0; nl < NL_; ++nl) { p[nl] = expf(p[nl] - mx); ss += p[nl]; }
    float inv = 1.0f / ss;
    #pragma unroll
    for (int nl = 0; nl < NL_; ++nl) p[nl] *= inv;
    unsigned used = 0; float v[3];
    #pragma unroll
    for (int k = 0; k < 3; ++k) {
        float best = -1.f; int bi = 0;
        #pragma unroll
        for (int nl = 0; nl < NL_; ++nl)
            if (!((used >> nl) & 1u) && p[nl] > best) { best = p[nl]; bi = nl; }
        used |= 1u << bi; idx[k] = bi; v[k] = best;
    }
    float x1 = expf(v[1] - v[0]), x2 = expf(v[2] - v[0]);
    float isw = 1.0f / (1.0f + x1 + x2);
    w[0] = isw; w[1] = x1 * isw; w[2] = x2 * isw;
}

// block-uniform "is layer nls selected by any expert" from RAW scores
// (top-3 of raw scores == top-3 of softmax probs; comparisons only)
__device__ __forceinline__ bool layer_selected(const float* __restrict__ gs,
                                               int b, int nls) {
    bool sel = false;
    #pragma unroll
    for (int e = 0; e < E_; ++e) {
        float v[NL_];
        #pragma unroll
        for (int nl = 0; nl < NL_; ++nl) v[nl] = gs[(b * NL_ + nl) * E_ + e];
        int i0 = 0, i1 = 0, i2 = 0; float bv = -1e30f;
        #pragma unroll
        for (int nl = 0; nl < NL_; ++nl) if (v[nl] > bv) { bv = v[nl]; i0 = nl; }
        bv = -1e30f;
        #pragma unroll
        for (int nl = 0; nl < NL_; ++nl)
            if (nl != i0 && v[nl] > bv) { bv = v[nl]; i1 = nl; }
        bv = -1e30f;
        #pragma unroll
        for (int nl = 0; nl < NL_; ++nl)
            if (nl != i0 && nl != i1 && v[nl] > bv) { bv = v[nl]; i2 = nl; }
        sel = sel || (i0 == nls) || (i1 == nls) || (i2 == nls);
    }
    return sel;
}

// ---------------------------------------------------------------------------
// Kernel 0 (prep): blocks [0,192): gate scores (one wave per (b,nl))
//                  blocks [192,288): WtB[j][k] = bf16(expert_W[e][k][c]), j=21e+c
// ---------------------------------------------------------------------------
__global__ __launch_bounds__(256) void prep_kernel(
        const float* __restrict__ feat, const float* __restrict__ gW,
        const float* __restrict__ gb, const float* __restrict__ eW,
        ushort_t* __restrict__ WtB, float* __restrict__ gs) {
    int blk = blockIdx.x, t = threadIdx.x;
    if (blk < B_ * NL_) {
        if (t < 64) {
            const float* cls = feat + (size_t)blk * L1_ * D_;
            float a0 = 0.f, a1 = 0.f, a2 = 0.f, a3 = 0.f;
            for (int q = 0; q < D_ / 64; ++q) {
                int d = t + 64 * q;
                float x = cls[d];
                float4 w = *(const float4*)(gW + (size_t)d * E_);
                a0 += x * w.x; a1 += x * w.y; a2 += x * w.z; a3 += x * w.w;
            }
            for (int off = 32; off > 0; off >>= 1) {
                a0 += __shfl_down(a0, off); a1 += __shfl_down(a1, off);
                a2 += __shfl_down(a2, off); a3 += __shfl_down(a3, off);
            }
            if (t == 0) {
                gs[blk * E_ + 0] = a0 + gb[0]; gs[blk * E_ + 1] = a1 + gb[1];
                gs[blk * E_ + 2] = a2 + gb[2]; gs[blk * E_ + 3] = a3 + gb[3];
            }
        }
    } else {
        int j = blk - B_ * NL_;                 // 0..95
        if (j < NJ_) {
            int e = j / C_, c = j % C_;
            for (int k = t; k < D_; k += 256)
                WtB[(size_t)j * D_ + k] = bf16rne(eW[((size_t)e * D_ + k) * C_ + c]);
        } else {
            for (int k = t; k < D_; k += 256) WtB[(size_t)j * D_ + k] = 0;
        }
    }
}

// ---------------------------------------------------------------------------
// Kernel 1 (GEMM): proj[b,nl,j,l] = feat[b,nl,1+l,:] . Wall[:,j]  (bf16 MFMA)
// R16 body verbatim (global_load_lds staging, linear LDS + pre-swizzled
// source, 1 barrier/K-step). ONLY change: selection flag derived inline
// from raw gate scores (block-uniform, ~50 VALU) -> select kernel removed.
// No per-frag gating (R7's mistake): all 6 frags computed unconditionally.
// ---------------------------------------------------------------------------
__global__ __launch_bounds__(256, 4) void gemm_kernel(
        const float* __restrict__ feat, const ushort_t* __restrict__ WtB,
        const float* __restrict__ gs, float* __restrict__ proj) {
    int blk = blockIdx.x;
    int tile = blk & 3;
    int bn = blk >> 2;                  // b*NL + nl
    if (!layer_selected(gs, bn / NL_, bn % NL_)) return;
    int rows_real = min(MT_, LP_ - tile * MT_);   // 52,52,52,40

    __shared__ f32x4  As4[2][64 * 8];   // 8 KiB per buffer (f32 rows of 128B)
    __shared__ short8 Bs[2][96 * 4];    // 6 KiB per buffer

    int t = threadIdx.x;
    int w = t >> 6, lane = t & 63;
    int la = lane & 15, kp = lane >> 4;

    // ---- A source precompute: wave w fills slots [w*128, w*128+128) ----
    const float* fbase = feat + ((size_t)bn * L1_ + 1 + tile * MT_) * D_;
    int sA0 = w * 128 + lane;
    int sA1 = sA0 + 64;
    int rA0 = sA0 >> 3, qA0 = (sA0 & 7) ^ (rA0 & 7);
    int rA1 = sA1 >> 3, qA1 = (sA1 & 7) ^ (rA1 & 7);
    const float* gA0 = fbase + (size_t)min(rA0, rows_real - 1) * D_ + qA0 * 4;
    const float* gA1 = fbase + (size_t)min(rA1, rows_real - 1) * D_ + qA1 * 4;

    // ---- B source precompute: slots 0-255 all waves; 256-383 waves 0,1 ----
    int sB0 = w * 64 + lane;
    int jB0 = sB0 >> 2, cB0 = sB0 & 3;
    int kgB0 = cB0 ^ (jB0 & 3) ^ (((jB0 >> 2) & 1) << 1);
    const ushort_t* gB0 = WtB + (size_t)jB0 * D_ + kgB0 * 8;
    int sB1 = 256 + w * 64 + lane;
    int jB1 = sB1 >> 2, cB1 = sB1 & 3;
    int kgB1 = cB1 ^ (jB1 & 3) ^ (((jB1 >> 2) & 1) << 1);
    const ushort_t* gB1 = WtB + (size_t)jB1 * D_ + kgB1 * 8;
    bool doB1 = (w < 2);

    // ---- fragment read indices ----
    int arow = w * 16 + la;
    int ar0 = arow * 8 + ((kp * 2) ^ (arow & 7));   // second read = ar0 ^ 1
    int bidx[6];
    #pragma unroll
    for (int nt = 0; nt < 6; ++nt) {
        int j = nt * 16 + la;
        bidx[nt] = j * 4 + (kp ^ (j & 3) ^ (((j >> 2) & 1) << 1));
    }

    // ---- prologue: stage step 0 into buffer 0 ----
    glds16(gA0, &As4[0][w * 128]);
    glds16(gA1, &As4[0][w * 128 + 64]);
    glds16(gB0, &Bs[0][w * 64]);
    if (doB1) glds16(gB1, &Bs[0][256 + w * 64]);
    __syncthreads();

    f32x4 acc[6];
    #pragma unroll
    for (int nt = 0; nt < 6; ++nt) acc[nt] = (f32x4)0.0f;

    for (int s = 0; s < KSTEPS; ++s) {
        int cur = s & 1;
        if (s + 1 < KSTEPS) {
            int k0 = (s + 1) * 32;
            glds16(gA0 + k0, &As4[cur ^ 1][w * 128]);
            glds16(gA1 + k0, &As4[cur ^ 1][w * 128 + 64]);
            glds16(gB0 + k0, &Bs[cur ^ 1][w * 64]);
            if (doB1) glds16(gB1 + k0, &Bs[cur ^ 1][256 + w * 64]);
        }
        {
            f32x4 a0 = As4[cur][ar0];
            f32x4 a1 = As4[cur][ar0 ^ 1];
            short8 af;
            #pragma unroll
            for (int i = 0; i < 4; ++i) {
                af[i]     = (short)bf16rne(a0[i]);
                af[i + 4] = (short)bf16rne(a1[i]);
            }
            #pragma unroll
            for (int nt = 0; nt < 6; ++nt)
                acc[nt] = __builtin_amdgcn_mfma_f32_16x16x32_bf16(
                    af, Bs[cur][bidx[nt]], acc[nt], 0, 0, 0);
        }
        __syncthreads();
    }

    // ---- epilogue: D frag: col = lane&15, rows = (lane>>4)*4 + i ----
    int lr = w * 16 + (kp << 2);
    int l0 = tile * MT_ + lr;
    if (lr < MT_ && l0 < LP_) {
        #pragma unroll
        for (int nt = 0; nt < 6; ++nt) {
            int j = nt * 16 + la;
            if (j < NJ_)
                *(f32x4*)(proj + ((size_t)bn * NJ_ + j) * LP_ + l0) = acc[nt];
        }
    }
}

// ---------------------------------------------------------------------------
// Kernel 2: inline per-b selection (4 threads -> LDS), gather selected proj
// rows, weight, expert-mean, bias; then bilinear upsample 14x14 -> 224x224.
// Block per (b, c, eighth-plane). Non-temporal stores (write-once output).
// ---------------------------------------------------------------------------
__global__ __launch_bounds__(256) void upsample_kernel(
        const float* __restrict__ proj, const float* __restrict__ gs,
        const float* __restrict__ eb, float* __restrict__ out) {
    int bq = blockIdx.x;
    int q = bq & 7;            // eighth: 28 output rows
    int bc = bq >> 3;          // b*C + c
    int b = bc / C_, c = bc % C_;
    int t = threadIdx.x;
    __shared__ float s[LP_];
    __shared__ int   sidx[E_][3];
    __shared__ float swgt[E_][3];
    if (t < E_) {
        int idx[3]; float wv[3];
        select_be(gs, b, t, idx, wv);
        #pragma unroll
        for (int k = 0; k < 3; ++k) { sidx[t][k] = idx[k]; swgt[t][k] = 0.25f * wv[k]; }
    }
    __syncthreads();
    if (t < LP_) {
        float a = 0.25f * (eb[c] + eb[C_ + c] + eb[2 * C_ + c] + eb[3 * C_ + c]);
        #pragma unroll
        for (int e = 0; e < E_; ++e) {
            #pragma unroll
            for (int k = 0; k < 3; ++k) {
                int nl = sidx[e][k];
                a += swgt[e][k] *
                     proj[(((size_t)b * NL_ + nl) * NJ_ + e * C_ + c) * LP_ + t];
            }
        }
        s[t] = a;
    }
    __syncthreads();
    f32x4* out4 = (f32x4*)out + (size_t)bc * IMG_ * (IMG_ / 4);
    for (int i = t; i < 28 * 56; i += 256) {
        int oy = q * 28 + i / 56;
        int ox4 = (i % 56) * 4;
        float fy = (oy + 0.5f) * 0.0625f - 0.5f;
        fy = fminf(fmaxf(fy, 0.0f), 13.0f);
        int y0 = (int)fy;
        float ty = fy - (float)y0;
        int y1 = min(y0 + 1, 13);
        const float* r0 = s + y0 * 14;
        const float* r1 = s + y1 * 14;
        f32x4 res;
        #pragma unroll
        for (int u = 0; u < 4; ++u) {
            int ox = ox4 + u;
            float fx = (ox + 0.5f) * 0.0625f - 0.5f;
            fx = fminf(fmaxf(fx, 0.0f), 13.0f);
            int x0 = (int)fx;
            float tx = fx - (float)x0;
            int x1 = min(x0 + 1, 13);
            float v00 = r0[x0], v01 = r0[x1];
            float v10 = r1[x0], v11 = r1[x1];
            float top = v00 + tx * (v01 - v00);
            float bot = v10 + tx * (v11 - v10);
            res[u] = top + ty * (bot - top);
        }
        __builtin_nontemporal_store(res, &out4[oy * 56 + (i % 56)]);
    }
}

// ---------------------------------------------------------------------------
extern "C" void kernel_launch(void* const* d_in, const int* in_sizes, int n_in,
                              void* d_out, int out_size, void* d_ws, size_t ws_size,
                              hipStream_t stream) {
    const float* feat = (const float*)d_in[0];   // (16, 12, 197, 768)
    const float* gW   = (const float*)d_in[1];   // (768, 4)
    const float* gb   = (const float*)d_in[2];   // (4,)
    const float* eW   = (const float*)d_in[3];   // (4, 768, 21)
    const float* eb   = (const float*)d_in[4];   // (4, 21)
    float* out = (float*)d_out;                  // (16, 21, 224, 224)

    float* ws = (float*)d_ws;
    float*    gs   = ws;                         // 768 f           [0,768)
    ushort_t* WtB  = (ushort_t*)(ws + 1536);     // 96*768 bf16     [1536,38400)
    float*    proj = ws + 38400;                 // 16*12*84*196 f  (~12.6 MB)

    hipLaunchKernelGGL(prep_kernel, dim3(B_ * NL_ + 96), dim3(256), 0, stream,
                       feat, gW, gb, eW, WtB, gs);
    hipLaunchKernelGGL(gemm_kernel, dim3(B_ * NL_ * 4), dim3(256), 0, stream,
                       feat, WtB, gs, proj);
    hipLaunchKernelGGL(upsample_kernel, dim3(B_ * C_ * 8), dim3(256), 0, stream,
                       proj, gs, eb, out);
}

// Round 18
// 51.187 us; speedup vs baseline: 1.0569x; 1.0569x over previous
//
#include <hip/hip_runtime.h>
#include <math.h>

// Problem constants
#define B_ 16
#define NL_ 12
#define L1_ 197
#define D_ 768
#define E_ 4
#define K_ 3
#define C_ 21
#define IMG_ 224
#define LP_ 196
#define NJ_ 84      // real output cols (E*C)
#define MT_ 52      // m-rows per gemm block (52,52,52,40)
#define KSTEPS 24   // 768 / 32

typedef __attribute__((ext_vector_type(8))) short short8;
typedef __attribute__((ext_vector_type(4))) float f32x4;
typedef unsigned short ushort_t;

__device__ __forceinline__ ushort_t bf16rne(float x) {
    unsigned u = __float_as_uint(x);
    unsigned r = (u + 0x7FFFu + ((u >> 16) & 1u)) >> 16;
    return (ushort_t)r;
}

// direct global -> LDS, 16 bytes per lane (dest = uniform base + lane*16)
__device__ __forceinline__ void glds16(const void* g, void* l) {
    __builtin_amdgcn_global_load_lds(
        (const __attribute__((address_space(1))) unsigned int*)g,
        (__attribute__((address_space(3))) unsigned int*)l, 16, 0, 0);
}

// per-(b,e) gating: softmax over 12 layers -> top3 (ties: lowest idx) -> softmax
__device__ __forceinline__ void select_be(const float* __restrict__ gs, int b, int e,
                                          int idx[3], float w[3]) {
    float p[NL_]; float mx = -1e30f;
    #pragma unroll
    for (int nl = 0; nl < NL_; ++nl) { float v = gs[(b * NL_ + nl) * E_ + e]; p[nl] = v; mx = fmaxf(mx, v); }
    float ss = 0.f;
    #pragma unroll
    for (int nl = 0; nl < NL_; ++nl) { p[nl] = expf(p[nl] - mx); ss += p[nl]; }
    float inv = 1.0f / ss;
    #pragma unroll
    for (int nl = 0; nl < NL_; ++nl) p[nl] *= inv;
    unsigned used = 0; float v[3];
    #pragma unroll
    for (int k = 0; k < 3; ++k) {
        float best = -1.f; int bi = 0;
        #pragma unroll
        for (int nl = 0; nl < NL_; ++nl)
            if (!((used >> nl) & 1u) && p[nl] > best) { best = p[nl]; bi = nl; }
        used |= 1u << bi; idx[k] = bi; v[k] = best;
    }
    float x1 = expf(v[1] - v[0]), x2 = expf(v[2] - v[0]);
    float isw = 1.0f / (1.0f + x1 + x2);
    w[0] = isw; w[1] = x1 * isw; w[2] = x2 * isw;
}

// ---------------------------------------------------------------------------
// Kernel 0 (prep): blocks [0,192): gate scores (one wave per (b,nl))
//                  blocks [192,288): WtB[j][k] = bf16(expert_W[e][k][c]), j=21e+c
// ---------------------------------------------------------------------------
__global__ __launch_bounds__(256) void prep_kernel(
        const float* __restrict__ feat, const float* __restrict__ gW,
        const float* __restrict__ gb, const float* __restrict__ eW,
        ushort_t* __restrict__ WtB, float* __restrict__ gs) {
    int blk = blockIdx.x, t = threadIdx.x;
    if (blk < B_ * NL_) {
        if (t < 64) {
            const float* cls = feat + (size_t)blk * L1_ * D_;
            float a0 = 0.f, a1 = 0.f, a2 = 0.f, a3 = 0.f;
            for (int q = 0; q < D_ / 64; ++q) {
                int d = t + 64 * q;
                float x = cls[d];
                float4 w = *(const float4*)(gW + (size_t)d * E_);
                a0 += x * w.x; a1 += x * w.y; a2 += x * w.z; a3 += x * w.w;
            }
            for (int off = 32; off > 0; off >>= 1) {
                a0 += __shfl_down(a0, off); a1 += __shfl_down(a1, off);
                a2 += __shfl_down(a2, off); a3 += __shfl_down(a3, off);
            }
            if (t == 0) {
                gs[blk * E_ + 0] = a0 + gb[0]; gs[blk * E_ + 1] = a1 + gb[1];
                gs[blk * E_ + 2] = a2 + gb[2]; gs[blk * E_ + 3] = a3 + gb[3];
            }
        }
    } else {
        int j = blk - B_ * NL_;                 // 0..95
        if (j < NJ_) {
            int e = j / C_, c = j % C_;
            for (int k = t; k < D_; k += 256)
                WtB[(size_t)j * D_ + k] = bf16rne(eW[((size_t)e * D_ + k) * C_ + c]);
        } else {
            for (int k = t; k < D_; k += 256) WtB[(size_t)j * D_ + k] = 0;
        }
    }
}

// ---------------------------------------------------------------------------
// Kernel 1 (select): 1 block. t<64: per-(b,e) top3+weights -> topi/wgt.
// t<192 (3 full waves): selected flag; wave-parallel ballot compaction ->
// dense list (sorted by bn) + count.
// ---------------------------------------------------------------------------
__global__ __launch_bounds__(256) void select_kernel(
        const float* __restrict__ gs, int* __restrict__ topi,
        float* __restrict__ wgt, int* __restrict__ list, int* __restrict__ nsel) {
    __shared__ int sidx[B_ * E_ * 3];
    __shared__ int wcnt[3];
    int t = threadIdx.x;
    if (t < B_ * E_) {
        int b = t >> 2, e = t & 3;
        int idx[3]; float w[3];
        select_be(gs, b, e, idx, w);
        #pragma unroll
        for (int k = 0; k < 3; ++k) {
            topi[t * 3 + k] = idx[k]; wgt[t * 3 + k] = w[k]; sidx[t * 3 + k] = idx[k];
        }
    }
    __syncthreads();
    int f = 0, rank = 0;
    if (t < B_ * NL_) {
        int b = t / NL_, nl = t % NL_;
        #pragma unroll
        for (int ek = 0; ek < 12; ++ek) f |= (sidx[b * 12 + ek] == nl);
        unsigned long long m = __ballot(f != 0);
        int lane = t & 63;
        rank = __popcll(m & ((1ull << lane) - 1ull));
        if (lane == 0) wcnt[t >> 6] = __popcll(m);
    }
    __syncthreads();
    if (t < B_ * NL_ && f) {
        int wv = t >> 6;
        int base = 0;
        if (wv > 0) base += wcnt[0];
        if (wv > 1) base += wcnt[1];
        list[base + rank] = t;
    }
    if (t == 0) nsel[0] = wcnt[0] + wcnt[1] + wcnt[2];
}

// ---------------------------------------------------------------------------
// Kernel 2 (GEMM): proj[b,nl,j,l] = feat[b,nl,1+l,:] . Wall[:,j]  (bf16 MFMA)
// Best measured (R16): direct global_load_lds staging (no VGPR round-trip,
// no ds_write), linear LDS + pre-swizzled per-lane global source (rule #21),
// depth-1 pipeline, 1 barrier/K-step, dense active-block prefix.
// ---------------------------------------------------------------------------
__global__ __launch_bounds__(256, 4) void gemm_kernel(
        const float* __restrict__ feat, const ushort_t* __restrict__ WtB,
        const int* __restrict__ list, const int* __restrict__ nsel,
        float* __restrict__ proj) {
    int blk = blockIdx.x;
    if (blk >= nsel[0] * 4) return;     // dense prefix of active blocks
    int tile = blk & 3;
    int bn = list[blk >> 2];            // b*NL + nl
    int rows_real = min(MT_, LP_ - tile * MT_);   // 52,52,52,40

    __shared__ f32x4  As4[2][64 * 8];   // 8 KiB per buffer (f32 rows of 128B)
    __shared__ short8 Bs[2][96 * 4];    // 6 KiB per buffer

    int t = threadIdx.x;
    int w = t >> 6, lane = t & 63;
    int la = lane & 15, kp = lane >> 4;

    // ---- A source precompute: wave w fills slots [w*128, w*128+128) ----
    const float* fbase = feat + ((size_t)bn * L1_ + 1 + tile * MT_) * D_;
    int sA0 = w * 128 + lane;
    int sA1 = sA0 + 64;
    int rA0 = sA0 >> 3, qA0 = (sA0 & 7) ^ (rA0 & 7);
    int rA1 = sA1 >> 3, qA1 = (sA1 & 7) ^ (rA1 & 7);
    const float* gA0 = fbase + (size_t)min(rA0, rows_real - 1) * D_ + qA0 * 4;
    const float* gA1 = fbase + (size_t)min(rA1, rows_real - 1) * D_ + qA1 * 4;

    // ---- B source precompute: slots 0-255 all waves; 256-383 waves 0,1 ----
    int sB0 = w * 64 + lane;
    int jB0 = sB0 >> 2, cB0 = sB0 & 3;
    int kgB0 = cB0 ^ (jB0 & 3) ^ (((jB0 >> 2) & 1) << 1);
    const ushort_t* gB0 = WtB + (size_t)jB0 * D_ + kgB0 * 8;
    int sB1 = 256 + w * 64 + lane;
    int jB1 = sB1 >> 2, cB1 = sB1 & 3;
    int kgB1 = cB1 ^ (jB1 & 3) ^ (((jB1 >> 2) & 1) << 1);
    const ushort_t* gB1 = WtB + (size_t)jB1 * D_ + kgB1 * 8;
    bool doB1 = (w < 2);

    // ---- fragment read indices ----
    int arow = w * 16 + la;
    int ar0 = arow * 8 + ((kp * 2) ^ (arow & 7));   // second read = ar0 ^ 1
    int bidx[6];
    #pragma unroll
    for (int nt = 0; nt < 6; ++nt) {
        int j = nt * 16 + la;
        bidx[nt] = j * 4 + (kp ^ (j & 3) ^ (((j >> 2) & 1) << 1));
    }

    // ---- prologue: stage step 0 into buffer 0 ----
    glds16(gA0, &As4[0][w * 128]);
    glds16(gA1, &As4[0][w * 128 + 64]);
    glds16(gB0, &Bs[0][w * 64]);
    if (doB1) glds16(gB1, &Bs[0][256 + w * 64]);
    __syncthreads();

    f32x4 acc[6];
    #pragma unroll
    for (int nt = 0; nt < 6; ++nt) acc[nt] = (f32x4)0.0f;

    for (int s = 0; s < KSTEPS; ++s) {
        int cur = s & 1;
        // issue next step's staging (lds-direct; drains at this step's barrier)
        if (s + 1 < KSTEPS) {
            int k0 = (s + 1) * 32;
            glds16(gA0 + k0, &As4[cur ^ 1][w * 128]);
            glds16(gA1 + k0, &As4[cur ^ 1][w * 128 + 64]);
            glds16(gB0 + k0, &Bs[cur ^ 1][w * 64]);
            if (doB1) glds16(gB1 + k0, &Bs[cur ^ 1][256 + w * 64]);
        }
        // compute current buffer: A f32 -> bf16 in-register, 6 MFMA
        {
            f32x4 a0 = As4[cur][ar0];
            f32x4 a1 = As4[cur][ar0 ^ 1];
            short8 af;
            #pragma unroll
            for (int i = 0; i < 4; ++i) {
                af[i]     = (short)bf16rne(a0[i]);
                af[i + 4] = (short)bf16rne(a1[i]);
            }
            #pragma unroll
            for (int nt = 0; nt < 6; ++nt)
                acc[nt] = __builtin_amdgcn_mfma_f32_16x16x32_bf16(
                    af, Bs[cur][bidx[nt]], acc[nt], 0, 0, 0);
        }
        __syncthreads();
    }

    // ---- epilogue: D frag: col = lane&15, rows = (lane>>4)*4 + i ----
    int lr = w * 16 + (kp << 2);
    int l0 = tile * MT_ + lr;
    if (lr < MT_ && l0 < LP_) {
        #pragma unroll
        for (int nt = 0; nt < 6; ++nt) {
            int j = nt * 16 + la;
            if (j < NJ_)
                *(f32x4*)(proj + ((size_t)bn * NJ_ + j) * LP_ + l0) = acc[nt];
        }
    }
}

// ---------------------------------------------------------------------------
// Kernel 3: gather selected proj rows, weight, expert-mean, bias;
// then bilinear upsample 14x14 -> 224x224. Block per (b, c, eighth-plane).
// Non-temporal stores (write-once output).
// ---------------------------------------------------------------------------
__global__ __launch_bounds__(256) void upsample_kernel(
        const float* __restrict__ proj, const int* __restrict__ topi,
        const float* __restrict__ wgt, const float* __restrict__ eb,
        float* __restrict__ out) {
    int bq = blockIdx.x;
    int q = bq & 7;            // eighth: 28 output rows
    int bc = bq >> 3;          // b*C + c
    int b = bc / C_, c = bc % C_;
    int t = threadIdx.x;
    __shared__ float s[LP_];
    if (t < LP_) {
        float a = 0.25f * (eb[c] + eb[C_ + c] + eb[2 * C_ + c] + eb[3 * C_ + c]);
        #pragma unroll
        for (int e = 0; e < E_; ++e) {
            int base = (b * E_ + e) * 3;
            #pragma unroll
            for (int k = 0; k < 3; ++k) {
                int nl = topi[base + k];
                float wv = 0.25f * wgt[base + k];
                a += wv * proj[(((size_t)b * NL_ + nl) * NJ_ + e * C_ + c) * LP_ + t];
            }
        }
        s[t] = a;
    }
    __syncthreads();
    f32x4* out4 = (f32x4*)out + (size_t)bc * IMG_ * (IMG_ / 4);
    for (int i = t; i < 28 * 56; i += 256) {
        int oy = q * 28 + i / 56;
        int ox4 = (i % 56) * 4;
        float fy = (oy + 0.5f) * 0.0625f - 0.5f;
        fy = fminf(fmaxf(fy, 0.0f), 13.0f);
        int y0 = (int)fy;
        float ty = fy - (float)y0;
        int y1 = min(y0 + 1, 13);
        const float* r0 = s + y0 * 14;
        const float* r1 = s + y1 * 14;
        f32x4 res;
        #pragma unroll
        for (int u = 0; u < 4; ++u) {
            int ox = ox4 + u;
            float fx = (ox + 0.5f) * 0.0625f - 0.5f;
            fx = fminf(fmaxf(fx, 0.0f), 13.0f);
            int x0 = (int)fx;
            float tx = fx - (float)x0;
            int x1 = min(x0 + 1, 13);
            float v00 = r0[x0], v01 = r0[x1];
            float v10 = r1[x0], v11 = r1[x1];
            float top = v00 + tx * (v01 - v00);
            float bot = v10 + tx * (v11 - v10);
            res[u] = top + ty * (bot - top);
        }
        __builtin_nontemporal_store(res, &out4[oy * 56 + (i % 56)]);
    }
}

// ---------------------------------------------------------------------------
extern "C" void kernel_launch(void* const* d_in, const int* in_sizes, int n_in,
                              void* d_out, int out_size, void* d_ws, size_t ws_size,
                              hipStream_t stream) {
    const float* feat = (const float*)d_in[0];   // (16, 12, 197, 768)
    const float* gW   = (const float*)d_in[1];   // (768, 4)
    const float* gb   = (const float*)d_in[2];   // (4,)
    const float* eW   = (const float*)d_in[3];   // (4, 768, 21)
    const float* eb   = (const float*)d_in[4];   // (4, 21)
    float* out = (float*)d_out;                  // (16, 21, 224, 224)

    float* ws = (float*)d_ws;
    float*    gs   = ws;                         // 768 f           [0,768)
    int*      topi = (int*)(ws + 768);           // 192             [768,960)
    float*    wgt  = ws + 960;                   // 192             [960,1152)
    int*      list = (int*)(ws + 1152);          // 192             [1152,1344)
    int*      nsel = (int*)(ws + 1344);          // 1               [1344,1345)
    ushort_t* WtB  = (ushort_t*)(ws + 1536);     // 96*768 bf16     [1536,38400)
    float*    proj = ws + 38400;                 // 16*12*84*196 f  (~12.6 MB)

    hipLaunchKernelGGL(prep_kernel, dim3(B_ * NL_ + 96), dim3(256), 0, stream,
                       feat, gW, gb, eW, WtB, gs);
    hipLaunchKernelGGL(select_kernel, dim3(1), dim3(256), 0, stream,
                       gs, topi, wgt, list, nsel);
    hipLaunchKernelGGL(gemm_kernel, dim3(B_ * NL_ * 4), dim3(256), 0, stream,
                       feat, WtB, list, nsel, proj);
    hipLaunchKernelGGL(upsample_kernel, dim3(B_ * C_ * 8), dim3(256), 0, stream,
                       proj, topi, wgt, eb, out);
}